// Round 11
// baseline (158.612 us; speedup 1.0000x reference)
//
#include <hip/hip_runtime.h>

#define NN 2304
#define CC 256
#define HH 8
#define HD 32
#define NYY 48
#define SCALE 0.17677669529663687f

typedef __bf16 bf16_t;
typedef __bf16 bf8v __attribute__((ext_vector_type(8)));
typedef float f4v __attribute__((ext_vector_type(4)));
typedef unsigned int u32x4 __attribute__((ext_vector_type(4)));

__device__ __forceinline__ f4v mfma16(bf8v a, bf8v b, f4v c) {
    return __builtin_amdgcn_mfma_f32_16x16x32_bf16(a, b, c, 0, 0, 0);
}

__device__ __forceinline__ bf8v cvt_w8(const float* p) {
    float4 a = *(const float4*)p;
    float4 c = *(const float4*)(p + 4);
    bf8v o;
    o[0] = (bf16_t)a.x; o[1] = (bf16_t)a.y; o[2] = (bf16_t)a.z; o[3] = (bf16_t)a.w;
    o[4] = (bf16_t)c.x; o[5] = (bf16_t)c.y; o[6] = (bf16_t)c.z; o[7] = (bf16_t)c.w;
    return o;
}

// pack two floats as bf16x2 in one dword (even key in low half)
__device__ __forceinline__ unsigned int pk2(float a, float b) {
    unsigned short lo = __builtin_bit_cast(unsigned short, (bf16_t)a);
    unsigned short hi = __builtin_bit_cast(unsigned short, (bf16_t)b);
    return ((unsigned int)hi << 16) | lo;
}

// softmax + in-register PV B-fragment assembly for one 32-key half.
// s0/s1: swapped-QK scores (keys kb+quad*4+r / kb+16+quad*4+r, q=l15).
__device__ __forceinline__ bf8v softmax_frag(
    f4v s0, f4v s1, int kb, int xiq, int yiq, int xi_lo, int xi_hi,
    const float* lds_emb, int quad, bool lowq, bool lowpair, bool keepown,
    float& lsum) {
    float p[8];
    const int xj_lo = kb / NYY;
    const int xj_hi = (kb + 31) / NYY;
    if (xj_lo > xi_hi + 5 || xj_hi + 5 < xi_lo) {
        // bias is 0 for the whole 32-key half (|dx|>5 everywhere)
#pragma unroll
        for (int r = 0; r < 4; r++) {
            p[r] = __expf(s0[r]);
            p[4 + r] = __expf(s1[r]);
        }
    } else {
#pragma unroll
        for (int r = 0; r < 4; r++) {
            int kj = kb + quad * 4 + r;
            int xj = kj / NYY;
            int yj = kj - xj * NYY;
            int dx = xiq - xj; dx = dx < 0 ? -dx : dx;
            int dy = yiq - yj; dy = dy < 0 ? -dy : dy;
            int tok = (dx > 5 || dy > 5) ? 36 : dx * 6 + dy;
            p[r] = __expf(s0[r] + lds_emb[tok]);
            int kj2 = kj + 16;
            int xj2 = kj2 / NYY;
            int yj2 = kj2 - xj2 * NYY;
            int dx2 = xiq - xj2; dx2 = dx2 < 0 ? -dx2 : dx2;
            int dy2 = yiq - yj2; dy2 = dy2 < 0 ? -dy2 : dy2;
            int tok2 = (dx2 > 5 || dy2 > 5) ? 36 : dx2 * 6 + dy2;
            p[4 + r] = __expf(s1[r] + lds_emb[tok2]);
        }
    }
    lsum += p[0] + p[1] + p[2] + p[3] + p[4] + p[5] + p[6] + p[7];

    unsigned int pk0 = pk2(p[0], p[1]);
    unsigned int pk1 = pk2(p[2], p[3]);
    unsigned int pk2_ = pk2(p[4], p[5]);
    unsigned int pk3 = pk2(p[6], p[7]);
    // xor16: partner quad within pair
    unsigned int x0 = __shfl_xor((int)pk0, 16);
    unsigned int x1 = __shfl_xor((int)pk1, 16);
    unsigned int x2 = __shfl_xor((int)pk2_, 16);
    unsigned int x3 = __shfl_xor((int)pk3, 16);
    unsigned int S0_0 = lowq ? pk0 : x0, S0_1 = lowq ? pk1 : x1;
    unsigned int S0_2 = lowq ? x0 : pk0, S0_3 = lowq ? x1 : pk1;
    unsigned int S1_0 = lowq ? pk2_ : x2, S1_1 = lowq ? pk3 : x3;
    unsigned int S1_2 = lowq ? x2 : pk2_, S1_3 = lowq ? x3 : pk3;
    // xor32: ship the set the partner pair needs
    unsigned int r0 = __shfl_xor((int)(lowpair ? S1_0 : S0_0), 32);
    unsigned int r1 = __shfl_xor((int)(lowpair ? S1_1 : S0_1), 32);
    unsigned int r2 = __shfl_xor((int)(lowpair ? S1_2 : S0_2), 32);
    unsigned int r3 = __shfl_xor((int)(lowpair ? S1_3 : S0_3), 32);
    u32x4 Bv;
    Bv.x = keepown ? (lowpair ? S0_0 : S1_0) : r0;
    Bv.y = keepown ? (lowpair ? S0_1 : S1_1) : r1;
    Bv.z = keepown ? (lowpair ? S0_2 : S1_2) : r2;
    Bv.w = keepown ? (lowpair ? S0_3 : S1_3) : r3;
    return __builtin_bit_cast(bf8v, Bv);
}

// ---------------------------------------------------------------------------
// Kernel 1: QKV projection GEMM (M=256 o, N=2304 n, K=256 c).
// W loaded f32 -> bf16 in-register; x staged per-block into LDS bf16
// transposed [n][c] with XOR swizzle (cb ^= n&7 on 16B groups).
// Block: 64 o x 32 n (4 waves, each 16o x 32n, 2 accumulators).
//   Q -> Qt (H, N, 32) pre-scaled; K -> Kt (H, N, 32); V -> Vd (H, 32, N)
// ---------------------------------------------------------------------------
__global__ __launch_bounds__(256) void k_proj_qkv(
    const float* __restrict__ Wq, const float* __restrict__ Wk,
    const float* __restrict__ Wv,
    const float* __restrict__ bq, const float* __restrict__ bk,
    const float* __restrict__ bv,
    const float* __restrict__ x,
    bf16_t* __restrict__ Qt, bf16_t* __restrict__ Kt, bf16_t* __restrict__ Vd) {
    const int mat = blockIdx.z;
    const float* Wf = (mat == 0) ? Wq : (mat == 1) ? Wk : Wv;
    const float* bias = (mat == 0) ? bq : (mat == 1) ? bk : bv;
    const int n0 = blockIdx.x * 32;
    const int o0 = blockIdx.y * 64;
    const int t = threadIdx.x;
    const int lane = t & 63;
    const int wave = t >> 6;
    const int l15 = lane & 15;
    const int quad = lane >> 4;
    const int orow = o0 + wave * 16;

    // ---- stage x[0..256][n0..n0+32) -> xs[n][c] bf16, swizzled ----
    __shared__ bf16_t xs[32][256];
    {
        const int sn = t & 31;       // n within tile
        const int scg = t >> 5;      // 0..7
#pragma unroll
        for (int i = 0; i < 4; i++) {
            const int cb = i * 8 + scg;          // 16B group index, 0..31
            const int c0s = cb * 8;
            bf8v o;
#pragma unroll
            for (int j = 0; j < 8; j++) {
                o[j] = (bf16_t)x[(size_t)(c0s + j) * NN + n0 + sn];
            }
            *(bf8v*)(&xs[sn][(cb ^ (sn & 7)) * 8]) = o;
        }
    }
    __syncthreads();

    f4v acc0 = {0.f, 0.f, 0.f, 0.f}, acc1 = {0.f, 0.f, 0.f, 0.f};
#pragma unroll
    for (int k0 = 0; k0 < CC; k0 += 32) {
        bf8v af = cvt_w8(Wf + (size_t)(orow + l15) * CC + k0 + quad * 8);
        const int pcb = ((k0 >> 3) + quad);
        bf8v b0 = *(const bf8v*)(&xs[l15][(pcb ^ (l15 & 7)) * 8]);
        bf8v b1 = *(const bf8v*)(&xs[16 + l15][(pcb ^ (l15 & 7)) * 8]);
        acc0 = mfma16(af, b0, acc0);
        acc1 = mfma16(af, b1, acc1);
    }

#pragma unroll
    for (int r = 0; r < 4; r++) {
        const int o = orow + quad * 4 + r;
        const float bo = bias[o];
#pragma unroll
        for (int nb = 0; nb < 2; nb++) {
            const int n = n0 + nb * 16 + l15;
            float v = (nb ? acc1[r] : acc0[r]) + bo;
            if (mat == 2) {
                Vd[(size_t)o * NN + n] = (bf16_t)v;
            } else {
                int h = o >> 5, d = o & 31;
                bf16_t* dst = (mat == 0) ? Qt : Kt;
                float vv = (mat == 0) ? v * SCALE : v;
                dst[(size_t)h * NN * HD + (size_t)n * HD + d] = (bf16_t)vv;
            }
        }
    }
}

// ---------------------------------------------------------------------------
// Kernel 2: fused attention, P in registers, 64-key iterations, manual
// software pipeline: iteration i+1's 8 K/V fragments prefetched into a
// second register set while computing iteration i (removes ~200cy L2 load
// latency from the dependent chain). Grid 1152 = 8 heads x 144 q-tiles of
// 16 rows; 4 waves = 4 key quarters (576 keys = 9 iters of 64).
// Swapped QK^T: s = mfma(K, Q) -> lane(l15,quad) holds P[key=quad*4+r][q=l15].
// 4-way cross-wave combine in LDS, normalize, write Yt (N x 256) bf16.
// ---------------------------------------------------------------------------
__global__ __launch_bounds__(256, 4) void k_attn(
    const bf16_t* __restrict__ Qt, const bf16_t* __restrict__ Kt,
    const bf16_t* __restrict__ Vd, const float* __restrict__ emb,
    bf16_t* __restrict__ Yt) {
    __shared__ float lds_emb[40];
    __shared__ float red[4][16][33];
    __shared__ float reds[4][16];
    const int b = blockIdx.x;
    const int h = b & 7;
    const int qt = b >> 3;
    const int t = threadIdx.x;
    if (t < 37) lds_emb[t] = (t < 36) ? emb[t * HH + h] : 0.0f;
    __syncthreads();

    const int wave = t >> 6, lane = t & 63;
    const int l15 = lane & 15, quad = lane >> 4;
    const int qg0 = qt * 16;
    const bf16_t* Qh = Qt + (size_t)h * NN * HD;
    const bf16_t* Kh = Kt + (size_t)h * NN * HD;
    const bf16_t* Vh = Vd + (size_t)h * HD * NN;

    const bf8v aq = *(const bf8v*)(Qh + (size_t)(qg0 + l15) * HD + quad * 8);

    const int qi = qg0 + l15;
    const int xiq = qi / NYY;
    const int yiq = qi - xiq * NYY;
    const int xi_lo = qg0 / NYY;            // wave-uniform (16 rows)
    const int xi_hi = (qg0 + 15) / NYY;

    f4v o0 = {0.f, 0.f, 0.f, 0.f}, o1 = {0.f, 0.f, 0.f, 0.f};
    const f4v z = {0.f, 0.f, 0.f, 0.f};
    float lsum = 0.f;
    const bool lowq = (quad & 1) == 0;
    const bool lowpair = quad < 2;
    const bool keepown = (quad == 0) || (quad == 3);

    const int k_begin = wave * (NN / 4);
    const int NITER = (NN / 4) / 64;        // 9

    // current-iteration fragment registers (static indices only)
    bf8v kc0, kc1, kc2, kc3, vc0, vc1, vc2, vc3;
    {
        const bf16_t* Kp = Kh + (size_t)k_begin * HD;
        kc0 = *(const bf8v*)(Kp + (size_t)l15 * HD + quad * 8);
        kc1 = *(const bf8v*)(Kp + (size_t)(16 + l15) * HD + quad * 8);
        kc2 = *(const bf8v*)(Kp + (size_t)(32 + l15) * HD + quad * 8);
        kc3 = *(const bf8v*)(Kp + (size_t)(48 + l15) * HD + quad * 8);
        vc0 = *(const bf8v*)(Vh + (size_t)l15 * NN + k_begin + quad * 8);
        vc1 = *(const bf8v*)(Vh + (size_t)(16 + l15) * NN + k_begin + quad * 8);
        vc2 = *(const bf8v*)(Vh + (size_t)l15 * NN + k_begin + 32 + quad * 8);
        vc3 = *(const bf8v*)(Vh + (size_t)(16 + l15) * NN + k_begin + 32 + quad * 8);
    }

    for (int it = 0; it < NITER; it++) {
        const int kb = k_begin + it * 64;

        // ---- prefetch next iteration's fragments (in flight during compute)
        bf8v kn0, kn1, kn2, kn3, vn0, vn1, vn2, vn3;
        if (it + 1 < NITER) {
            const int kb2 = kb + 64;
            const bf16_t* Kp2 = Kh + (size_t)kb2 * HD;
            kn0 = *(const bf8v*)(Kp2 + (size_t)l15 * HD + quad * 8);
            kn1 = *(const bf8v*)(Kp2 + (size_t)(16 + l15) * HD + quad * 8);
            kn2 = *(const bf8v*)(Kp2 + (size_t)(32 + l15) * HD + quad * 8);
            kn3 = *(const bf8v*)(Kp2 + (size_t)(48 + l15) * HD + quad * 8);
            vn0 = *(const bf8v*)(Vh + (size_t)l15 * NN + kb2 + quad * 8);
            vn1 = *(const bf8v*)(Vh + (size_t)(16 + l15) * NN + kb2 + quad * 8);
            vn2 = *(const bf8v*)(Vh + (size_t)l15 * NN + kb2 + 32 + quad * 8);
            vn3 = *(const bf8v*)(Vh + (size_t)(16 + l15) * NN + kb2 + 32 + quad * 8);
        }

        // ---- compute on current fragments
        f4v s0a = mfma16(kc0, aq, z);
        f4v s1a = mfma16(kc1, aq, z);
        f4v s0b = mfma16(kc2, aq, z);
        f4v s1b = mfma16(kc3, aq, z);

        bf8v pbA = softmax_frag(s0a, s1a, kb, xiq, yiq, xi_lo, xi_hi,
                                lds_emb, quad, lowq, lowpair, keepown, lsum);
        bf8v pbB = softmax_frag(s0b, s1b, kb + 32, xiq, yiq, xi_lo, xi_hi,
                                lds_emb, quad, lowq, lowpair, keepown, lsum);

        o0 = mfma16(vc0, pbA, o0);
        o1 = mfma16(vc1, pbA, o1);
        o0 = mfma16(vc2, pbB, o0);
        o1 = mfma16(vc3, pbB, o1);

        // ---- rotate
        if (it + 1 < NITER) {
            kc0 = kn0; kc1 = kn1; kc2 = kn2; kc3 = kn3;
            vc0 = vn0; vc1 = vn1; vc2 = vn2; vc3 = vn3;
        }
    }

    // reduce lsum across quads (per q = l15)
    float v = lsum;
    v += __shfl_xor(v, 16);
    v += __shfl_xor(v, 32);

    // stash per-wave partials: red[wave][q][d]
#pragma unroll
    for (int r = 0; r < 4; r++) {
        red[wave][l15][quad * 4 + r] = o0[r];
        red[wave][l15][16 + quad * 4 + r] = o1[r];
    }
    if (lane < 16) reds[wave][lane] = v;
    __syncthreads();

    // combine the 4 key-quarters, normalize, write Yt
#pragma unroll
    for (int e = t; e < 512; e += 256) {
        const int row = e >> 5;
        const int d = e & 31;
        float so = red[0][row][d] + red[1][row][d] + red[2][row][d] + red[3][row][d];
        float sl = reds[0][row] + reds[1][row] + reds[2][row] + reds[3][row];
        Yt[(size_t)(qg0 + row) * CC + h * HD + d] = (bf16_t)(so / sl);
    }
}

// ---------------------------------------------------------------------------
// Kernel 3: output projection (M=256, N=2304, K=256).
// Wp loaded f32 -> bf16 in-register; Yt bf16 from k_attn. fp32 out + bias.
// Block: 64 o x 32 n.
// ---------------------------------------------------------------------------
__global__ __launch_bounds__(256) void k_proj_out(
    const float* __restrict__ Wp, const float* __restrict__ bp,
    const bf16_t* __restrict__ Yt, float* __restrict__ out) {
    const int n0 = blockIdx.x * 32;
    const int o0 = blockIdx.y * 64;
    const int lane = threadIdx.x & 63;
    const int wave = threadIdx.x >> 6;
    const int l15 = lane & 15;
    const int quad = lane >> 4;
    const int orow = o0 + wave * 16;

    f4v acc0 = {0.f, 0.f, 0.f, 0.f}, acc1 = {0.f, 0.f, 0.f, 0.f};
#pragma unroll
    for (int k0 = 0; k0 < CC; k0 += 32) {
        bf8v af = cvt_w8(Wp + (size_t)(orow + l15) * CC + k0 + quad * 8);
        bf8v b0 = *(const bf8v*)(Yt + (size_t)(n0 + l15) * CC + k0 + quad * 8);
        bf8v b1 = *(const bf8v*)(Yt + (size_t)(n0 + 16 + l15) * CC + k0 + quad * 8);
        acc0 = mfma16(af, b0, acc0);
        acc1 = mfma16(af, b1, acc1);
    }

#pragma unroll
    for (int r = 0; r < 4; r++) {
        const int o = orow + quad * 4 + r;
        const float bo = bp[o];
        out[(size_t)o * NN + n0 + l15] = acc0[r] + bo;
        out[(size_t)o * NN + n0 + 16 + l15] = acc1[r] + bo;
    }
}

// ---------------------------------------------------------------------------
extern "C" void kernel_launch(void* const* d_in, const int* in_sizes, int n_in,
                              void* d_out, int out_size, void* d_ws, size_t ws_size,
                              hipStream_t stream) {
    const float* x   = (const float*)d_in[0];
    const float* Wq  = (const float*)d_in[1];
    const float* bq  = (const float*)d_in[2];
    const float* Wk  = (const float*)d_in[3];
    const float* bk  = (const float*)d_in[4];
    const float* Wv  = (const float*)d_in[5];
    const float* bv  = (const float*)d_in[6];
    const float* Wp  = (const float*)d_in[7];
    const float* bp  = (const float*)d_in[8];
    const float* emb = (const float*)d_in[9];
    // d_in[10] = tokens: recomputed analytically in-kernel, never read.
    float* out = (float*)d_out;

    bf16_t* Qt = (bf16_t*)d_ws;              // (H, N, 32)
    bf16_t* Kt = Qt + (size_t)NN * CC;       // (H, N, 32)
    bf16_t* Vd = Kt + (size_t)NN * CC;       // (H, 32, N)
    bf16_t* Yt = Vd + (size_t)NN * CC;       // (N, 256)

    hipLaunchKernelGGL(k_proj_qkv, dim3(72, 4, 3), dim3(256), 0, stream,
                       Wq, Wk, Wv, bq, bk, bv, x, Qt, Kt, Vd);
    hipLaunchKernelGGL(k_attn, dim3(1152), dim3(256), 0, stream,
                       Qt, Kt, Vd, emb, Yt);
    hipLaunchKernelGGL(k_proj_out, dim3(72, 4), dim3(256), 0, stream, Wp, bp, Yt, out);
}

// Round 12
// 139.953 us; speedup vs baseline: 1.1333x; 1.1333x over previous
//
#include <hip/hip_runtime.h>

#define NN 2304
#define CC 256
#define HH 8
#define HD 32
#define NYY 48
#define SCALE 0.17677669529663687f

typedef __bf16 bf16_t;
typedef __bf16 bf8v __attribute__((ext_vector_type(8)));
typedef float f4v __attribute__((ext_vector_type(4)));

__device__ __forceinline__ f4v mfma16(bf8v a, bf8v b, f4v c) {
    return __builtin_amdgcn_mfma_f32_16x16x32_bf16(a, b, c, 0, 0, 0);
}

__device__ __forceinline__ bf8v cvt_w8(const float* p) {
    float4 a = *(const float4*)p;
    float4 c = *(const float4*)(p + 4);
    bf8v o;
    o[0] = (bf16_t)a.x; o[1] = (bf16_t)a.y; o[2] = (bf16_t)a.z; o[3] = (bf16_t)a.w;
    o[4] = (bf16_t)c.x; o[5] = (bf16_t)c.y; o[6] = (bf16_t)c.z; o[7] = (bf16_t)c.w;
    return o;
}

// ---------------------------------------------------------------------------
// Kernel 1: QKV projection GEMM (M=256 o, N=2304 n, K=256 c).
// W loaded f32 -> bf16 in-register; x staged per-block into LDS bf16
// transposed [n][c] with XOR swizzle (cb ^= n&7 on 16B groups):
// write ~4-way conflict (one-time), ds_read_b128 ~2-way (free).
// Block: 64 o x 32 n (4 waves, each 16o x 32n, 2 accumulators).
//   Q -> Qt (H, N, 32) pre-scaled; K -> Kt (H, N, 32); V -> Vd (H, 32, N)
// ---------------------------------------------------------------------------
__global__ __launch_bounds__(256) void k_proj_qkv(
    const float* __restrict__ Wq, const float* __restrict__ Wk,
    const float* __restrict__ Wv,
    const float* __restrict__ bq, const float* __restrict__ bk,
    const float* __restrict__ bv,
    const float* __restrict__ x,
    bf16_t* __restrict__ Qt, bf16_t* __restrict__ Kt, bf16_t* __restrict__ Vd) {
    const int mat = blockIdx.z;
    const float* Wf = (mat == 0) ? Wq : (mat == 1) ? Wk : Wv;
    const float* bias = (mat == 0) ? bq : (mat == 1) ? bk : bv;
    const int n0 = blockIdx.x * 32;
    const int o0 = blockIdx.y * 64;
    const int t = threadIdx.x;
    const int lane = t & 63;
    const int wave = t >> 6;
    const int l15 = lane & 15;
    const int quad = lane >> 4;
    const int orow = o0 + wave * 16;

    // ---- stage x[0..256][n0..n0+32) -> xs[n][c] bf16, swizzled ----
    __shared__ bf16_t xs[32][256];
    {
        const int sn = t & 31;       // n within tile
        const int scg = t >> 5;      // 0..7
#pragma unroll
        for (int i = 0; i < 4; i++) {
            const int cb = i * 8 + scg;          // 16B group index, 0..31
            const int c0s = cb * 8;
            bf8v o;
#pragma unroll
            for (int j = 0; j < 8; j++) {
                o[j] = (bf16_t)x[(size_t)(c0s + j) * NN + n0 + sn];
            }
            *(bf8v*)(&xs[sn][(cb ^ (sn & 7)) * 8]) = o;
        }
    }
    __syncthreads();

    f4v acc0 = {0.f, 0.f, 0.f, 0.f}, acc1 = {0.f, 0.f, 0.f, 0.f};
#pragma unroll
    for (int k0 = 0; k0 < CC; k0 += 32) {
        bf8v af = cvt_w8(Wf + (size_t)(orow + l15) * CC + k0 + quad * 8);
        const int pcb = ((k0 >> 3) + quad);
        bf8v b0 = *(const bf8v*)(&xs[l15][(pcb ^ (l15 & 7)) * 8]);
        bf8v b1 = *(const bf8v*)(&xs[16 + l15][(pcb ^ (l15 & 7)) * 8]);
        acc0 = mfma16(af, b0, acc0);
        acc1 = mfma16(af, b1, acc1);
    }

#pragma unroll
    for (int r = 0; r < 4; r++) {
        const int o = orow + quad * 4 + r;
        const float bo = bias[o];
#pragma unroll
        for (int nb = 0; nb < 2; nb++) {
            const int n = n0 + nb * 16 + l15;
            float v = (nb ? acc1[r] : acc0[r]) + bo;
            if (mat == 2) {
                Vd[(size_t)o * NN + n] = (bf16_t)v;
            } else {
                int h = o >> 5, d = o & 31;
                bf16_t* dst = (mat == 0) ? Qt : Kt;
                float vv = (mat == 0) ? v * SCALE : v;
                dst[(size_t)h * NN * HD + (size_t)n * HD + d] = (bf16_t)vv;
            }
        }
    }
}

// ---------------------------------------------------------------------------
// Kernel 2: fused attention, split-K inside the block (no partial round-trip).
// Grid 1152 = 8 heads x 144 q-tiles of 16 rows. All 4 waves share the same
// 16 q-rows; wave w handles keys [w*576, (w+1)*576). Partials combined in
// LDS, normalized, written directly to Yt (N x 256) bf16.
// ---------------------------------------------------------------------------
__global__ __launch_bounds__(256, 4) void k_attn(
    const bf16_t* __restrict__ Qt, const bf16_t* __restrict__ Kt,
    const bf16_t* __restrict__ Vd, const float* __restrict__ emb,
    bf16_t* __restrict__ Yt) {
    __shared__ float lds_emb[40];
    __shared__ float red[4][16][33];   // +1 pad: 2-way max on write
    __shared__ float reds[4][16];
    __shared__ bf16_t lds_p[4][16 * 32];
    const int b = blockIdx.x;
    const int h = b & 7;
    const int qt = b >> 3;
    const int t = threadIdx.x;
    if (t < 37) lds_emb[t] = (t < 36) ? emb[t * HH + h] : 0.0f;
    __syncthreads();

    const int wave = t >> 6, lane = t & 63;
    const int l15 = lane & 15, quad = lane >> 4;
    const int qg0 = qt * 16;
    const bf16_t* Qh = Qt + (size_t)h * NN * HD;
    const bf16_t* Kh = Kt + (size_t)h * NN * HD;
    const bf16_t* Vh = Vd + (size_t)h * HD * NN;

    const bf8v aq = *(const bf8v*)(Qh + (size_t)(qg0 + l15) * HD + quad * 8);

    int xi[4], yi[4];
#pragma unroll
    for (int r = 0; r < 4; r++) {
        int qi = qg0 + quad * 4 + r;
        xi[r] = qi / NYY;
        yi[r] = qi - xi[r] * NYY;
    }
    const int xi_lo = qg0 / NYY;            // wave-uniform (16 rows)
    const int xi_hi = (qg0 + 15) / NYY;

    f4v o0 = {0.f, 0.f, 0.f, 0.f}, o1 = {0.f, 0.f, 0.f, 0.f};
    const f4v z = {0.f, 0.f, 0.f, 0.f};
    float lsum[4] = {0.f, 0.f, 0.f, 0.f};
    bf16_t* plds = &lds_p[wave][0];

    const int k_begin = wave * (NN / 4), k_end = k_begin + NN / 4;
    for (int kb = k_begin; kb < k_end; kb += 32) {
        bf8v kf0 = *(const bf8v*)(Kh + (size_t)(kb + l15) * HD + quad * 8);
        bf8v kf1 = *(const bf8v*)(Kh + (size_t)(kb + 16 + l15) * HD + quad * 8);
        bf8v vf0 = *(const bf8v*)(Vh + (size_t)l15 * NN + kb + quad * 8);
        bf8v vf1 = *(const bf8v*)(Vh + (size_t)(16 + l15) * NN + kb + quad * 8);
        f4v s0 = mfma16(aq, kf0, z);
        f4v s1 = mfma16(aq, kf1, z);

        // Bias is 0 whenever |dx|>5: skip token math for chunks whose whole
        // x-range is out of window (wave-uniform branch, ~75% of chunks).
        const int xj_lo = kb / NYY;
        const int xj_hi = (kb + 31) / NYY;
        if (xj_lo > xi_hi + 5 || xj_hi + 5 < xi_lo) {
#pragma unroll
            for (int cb = 0; cb < 2; cb++) {
                const f4v& s = cb ? s1 : s0;
#pragma unroll
                for (int r = 0; r < 4; r++) {
                    float p = __expf(s[r]);
                    lsum[r] += p;
                    plds[(quad * 4 + r) * 32 + cb * 16 + l15] = (bf16_t)p;
                }
            }
        } else {
#pragma unroll
            for (int cb = 0; cb < 2; cb++) {
                const f4v& s = cb ? s1 : s0;
                int kj = kb + cb * 16 + l15;
                int xj = kj / NYY;
                int yj = kj - xj * NYY;
#pragma unroll
                for (int r = 0; r < 4; r++) {
                    int dx = xi[r] - xj; dx = dx < 0 ? -dx : dx;
                    int dy = yi[r] - yj; dy = dy < 0 ? -dy : dy;
                    int tok = (dx > 5 || dy > 5) ? 36 : dx * 6 + dy;
                    float p = __expf(s[r] + lds_emb[tok]);
                    lsum[r] += p;
                    plds[(quad * 4 + r) * 32 + cb * 16 + l15] = (bf16_t)p;
                }
            }
        }
        bf8v ap = *(const bf8v*)(plds + l15 * 32 + quad * 8);
        o0 = mfma16(ap, vf0, o0);
        o1 = mfma16(ap, vf1, o1);
    }

    // Stash per-wave partials in LDS.
#pragma unroll
    for (int r = 0; r < 4; r++) {
        float v = lsum[r];
#pragma unroll
        for (int m = 1; m < 16; m <<= 1) v += __shfl_xor(v, m, 64);
        const int row = quad * 4 + r;
        red[wave][row][l15] = o0[r];
        red[wave][row][16 + l15] = o1[r];
        if (l15 == 0) reds[wave][row] = v;
    }
    __syncthreads();

    // Combine across the 4 waves, normalize, write Yt.
#pragma unroll
    for (int e = t; e < 512; e += 256) {
        const int row = e >> 5;
        const int d = e & 31;
        float so = red[0][row][d] + red[1][row][d] + red[2][row][d] + red[3][row][d];
        float sl = reds[0][row] + reds[1][row] + reds[2][row] + reds[3][row];
        Yt[(size_t)(qg0 + row) * CC + h * HD + d] = (bf16_t)(so / sl);
    }
}

// ---------------------------------------------------------------------------
// Kernel 3: output projection (M=256, N=2304, K=256).
// Wp loaded f32 -> bf16 in-register; Yt bf16 from k_attn. fp32 out + bias.
// Block: 64 o x 32 n.
// ---------------------------------------------------------------------------
__global__ __launch_bounds__(256) void k_proj_out(
    const float* __restrict__ Wp, const float* __restrict__ bp,
    const bf16_t* __restrict__ Yt, float* __restrict__ out) {
    const int n0 = blockIdx.x * 32;
    const int o0 = blockIdx.y * 64;
    const int lane = threadIdx.x & 63;
    const int wave = threadIdx.x >> 6;
    const int l15 = lane & 15;
    const int quad = lane >> 4;
    const int orow = o0 + wave * 16;

    f4v acc0 = {0.f, 0.f, 0.f, 0.f}, acc1 = {0.f, 0.f, 0.f, 0.f};
#pragma unroll
    for (int k0 = 0; k0 < CC; k0 += 32) {
        bf8v af = cvt_w8(Wp + (size_t)(orow + l15) * CC + k0 + quad * 8);
        bf8v b0 = *(const bf8v*)(Yt + (size_t)(n0 + l15) * CC + k0 + quad * 8);
        bf8v b1 = *(const bf8v*)(Yt + (size_t)(n0 + 16 + l15) * CC + k0 + quad * 8);
        acc0 = mfma16(af, b0, acc0);
        acc1 = mfma16(af, b1, acc1);
    }

#pragma unroll
    for (int r = 0; r < 4; r++) {
        const int o = orow + quad * 4 + r;
        const float bo = bp[o];
        out[(size_t)o * NN + n0 + l15] = acc0[r] + bo;
        out[(size_t)o * NN + n0 + 16 + l15] = acc1[r] + bo;
    }
}

// ---------------------------------------------------------------------------
extern "C" void kernel_launch(void* const* d_in, const int* in_sizes, int n_in,
                              void* d_out, int out_size, void* d_ws, size_t ws_size,
                              hipStream_t stream) {
    const float* x   = (const float*)d_in[0];
    const float* Wq  = (const float*)d_in[1];
    const float* bq  = (const float*)d_in[2];
    const float* Wk  = (const float*)d_in[3];
    const float* bk  = (const float*)d_in[4];
    const float* Wv  = (const float*)d_in[5];
    const float* bv  = (const float*)d_in[6];
    const float* Wp  = (const float*)d_in[7];
    const float* bp  = (const float*)d_in[8];
    const float* emb = (const float*)d_in[9];
    // d_in[10] = tokens: recomputed analytically in-kernel, never read.
    float* out = (float*)d_out;

    bf16_t* Qt = (bf16_t*)d_ws;              // (H, N, 32)
    bf16_t* Kt = Qt + (size_t)NN * CC;       // (H, N, 32)
    bf16_t* Vd = Kt + (size_t)NN * CC;       // (H, 32, N)
    bf16_t* Yt = Vd + (size_t)NN * CC;       // (N, 256)

    hipLaunchKernelGGL(k_proj_qkv, dim3(72, 4, 3), dim3(256), 0, stream,
                       Wq, Wk, Wv, bq, bk, bv, x, Qt, Kt, Vd);
    hipLaunchKernelGGL(k_attn, dim3(1152), dim3(256), 0, stream,
                       Qt, Kt, Vd, emb, Yt);
    hipLaunchKernelGGL(k_proj_out, dim3(72, 4), dim3(256), 0, stream, Wp, bp, Yt, out);
}